// Round 1
// baseline (3279.552 us; speedup 1.0000x reference)
//
#include <hip/hip_runtime.h>
#include <stdint.h>

#define NPTS 8192
#define NBATCH 8
#define NPOINT 2048
#define KNN_K 16
#define CIN 64
#define COUT 128

typedef unsigned long long u64;
typedef unsigned int u32;

// ---------------- Kernel 1: farthest point sampling ----------------
// grid NBATCH, block 512. Each thread owns 16 points (strided by 512).
__global__ __launch_bounds__(512) void fps_kernel(const float* __restrict__ xyz,
                                                  int* __restrict__ cent) {
  const int b = blockIdx.x;
  const int tid = threadIdx.x;
  const float* xb = xyz + (size_t)b * NPTS * 3;
  float px[16], py[16], pz[16], dist[16];
#pragma unroll
  for (int j = 0; j < 16; ++j) {
    int i = tid + 512 * j;
    px[j] = xb[i * 3 + 0];
    py[j] = xb[i * 3 + 1];
    pz[j] = xb[i * 3 + 2];
    dist[j] = 1e10f;
  }
  __shared__ u64 kbuf[8];
  __shared__ float cbuf[3];
  if (tid == 0) {
    cent[b * NPOINT] = 0;
    cbuf[0] = px[0]; cbuf[1] = py[0]; cbuf[2] = pz[0];
  }
  __syncthreads();
  float cx = cbuf[0], cy = cbuf[1], cz = cbuf[2];
  const int lane = tid & 63;
  const int wid = tid >> 6;  // 8 waves

  for (int it = 1; it < NPOINT; ++it) {
    float bv = -1.0f;
    int bj = 0;
#pragma unroll
    for (int j = 0; j < 16; ++j) {
      float dx = px[j] - cx, dy = py[j] - cy, dz = pz[j] - cz;
      float dd = dx * dx + dy * dy + dz * dz;
      float nd = fminf(dist[j], dd);
      dist[j] = nd;
      if (nd > bv) { bv = nd; bj = j; }  // ascending j => first-index tie-break
    }
    u32 idx = (u32)(tid + (bj << 9));
    // max-key: larger distance wins; equal distance -> smaller index wins
    u64 key = ((u64)__float_as_uint(bv) << 32) | (u64)(0xFFFFFFFFu - idx);
#pragma unroll
    for (int off = 32; off >= 1; off >>= 1) {
      u64 other = __shfl_xor(key, off, 64);
      key = (other > key) ? other : key;
    }
    if (lane == 0) kbuf[wid] = key;
    __syncthreads();
    u64 k2 = kbuf[lane & 7];
#pragma unroll
    for (int off = 4; off >= 1; off >>= 1) {
      u64 other = __shfl_xor(k2, off, 64);
      k2 = (other > k2) ? other : k2;
    }
    u32 widx = 0xFFFFFFFFu - (u32)(k2 & 0xFFFFFFFFu);
    if (tid == (int)(widx & 511u)) {
      int j0 = (int)(widx >> 9);
      float nx = px[0], ny = py[0], nz = pz[0];
#pragma unroll
      for (int j = 1; j < 16; ++j) {
        if (j == j0) { nx = px[j]; ny = py[j]; nz = pz[j]; }
      }
      cbuf[0] = nx; cbuf[1] = ny; cbuf[2] = nz;
      cent[b * NPOINT + it] = (int)widx;
    }
    __syncthreads();
    cx = cbuf[0]; cy = cbuf[1]; cz = cbuf[2];
  }
}

// ---------------- Kernel 2: 16-NN per centroid + new_xyz gather ----------------
// grid NBATCH*NPOINT, block 256. 32 candidate dists per thread in registers.
__global__ __launch_bounds__(256) void knn_kernel(const float* __restrict__ xyz,
                                                  const int* __restrict__ cent,
                                                  int* __restrict__ knn,
                                                  float* __restrict__ out_xyz) {
  const int pt = blockIdx.x;       // 0..16383
  const int b = pt >> 11;
  const int tid = threadIdx.x;
  const float* xb = xyz + (size_t)b * NPTS * 3;
  const int ci = cent[pt];
  const float mx = xb[ci * 3 + 0], my = xb[ci * 3 + 1], mz = xb[ci * 3 + 2];
  if (tid < 3) out_xyz[pt * 3 + tid] = xb[ci * 3 + tid];
  const float sm = mx * mx + my * my + mz * mz;

  float d[32];
  float lv = 3.0e38f;
  int lj = 0;
#pragma unroll
  for (int j = 0; j < 32; ++j) {
    int i = tid + 256 * j;
    float x = xb[i * 3 + 0], y = xb[i * 3 + 1], z = xb[i * 3 + 2];
    float dot = mx * x + my * y + mz * z;
    float sp = x * x + y * y + z * z;
    float dd = -2.0f * dot + sm + sp;   // same assoc as reference
    d[j] = dd;
    if (dd < lv) { lv = dd; lj = j; }
  }

  __shared__ u64 kbuf[2][4];
  const int lane = tid & 63;
  const int wid = tid >> 6;  // 4 waves

  for (int p = 0; p < KNN_K; ++p) {
    u32 fb = __float_as_uint(lv);
    u32 mapped = (fb & 0x80000000u) ? ~fb : (fb | 0x80000000u);  // order-preserving
    u32 idx = (u32)(tid + (lj << 8));  // == point index
    u64 key = ((u64)mapped << 32) | (u64)idx;  // min-key: smaller d, then smaller idx
#pragma unroll
    for (int off = 32; off >= 1; off >>= 1) {
      u64 other = __shfl_xor(key, off, 64);
      key = (other < key) ? other : key;
    }
    if (lane == 0) kbuf[p & 1][wid] = key;
    __syncthreads();
    u64 k2 = kbuf[p & 1][lane & 3];
#pragma unroll
    for (int off = 2; off >= 1; off >>= 1) {
      u64 other = __shfl_xor(k2, off, 64);
      k2 = (other < k2) ? other : k2;
    }
    u32 widx = (u32)(k2 & 0xFFFFFFFFu);
    if (tid == 0) knn[pt * KNN_K + p] = (int)widx;
    if (tid == (int)(widx & 255u)) {
      int j0 = (int)(widx >> 8);
      float nlv = 3.0e38f;
      int nlj = 0;
#pragma unroll
      for (int j = 0; j < 32; ++j) {
        if (j == j0) d[j] = 3.0e38f;
        if (d[j] < nlv) { nlv = d[j]; nlj = j; }
      }
      lv = nlv; lj = nlj;
    }
    // no second barrier needed: kbuf is double-buffered
  }
}

// ---------------- Kernel 3: gather+GEMM, per-block BN partial sums ----------------
// grid 2048, block 256: 128 rows per block. o = tid&127, grp = tid>>7.
__global__ __launch_bounds__(256) void gemm_stats_kernel(const float* __restrict__ feat,
                                                         const float* __restrict__ W,
                                                         const int* __restrict__ knn,
                                                         float* __restrict__ part) {
  const int tid = threadIdx.x;
  const int o = tid & 127;
  const int grp = tid >> 7;
  float w[64];
  {
    const float4* wv = (const float4*)(W + (size_t)o * CIN);
#pragma unroll
    for (int q = 0; q < 16; ++q) {
      float4 v = wv[q];
      w[q * 4 + 0] = v.x; w[q * 4 + 1] = v.y; w[q * 4 + 2] = v.z; w[q * 4 + 3] = v.w;
    }
  }
  __shared__ __align__(16) float g[8][CIN];
  __shared__ float red[256];
  float s1 = 0.f, s2 = 0.f;
  const int rowbase0 = blockIdx.x * 128;

  for (int pass = 0; pass < 16; ++pass) {
    const int rowbase = rowbase0 + pass * 8;
    __syncthreads();
    if (tid < 128) {
      int r = rowbase + (tid >> 4);
      int pidx = knn[r];
      int bb = r >> 15;  // 32768 rows per batch
      const float4* src = (const float4*)(feat + (size_t)(bb * NPTS + pidx) * CIN);
      *((float4*)&g[tid >> 4][(tid & 15) * 4]) = src[tid & 15];
    }
    __syncthreads();
    float acc0 = 0.f, acc1 = 0.f, acc2 = 0.f, acc3 = 0.f;
#pragma unroll
    for (int q = 0; q < 16; ++q) {
      float4 a0 = *((const float4*)&g[grp * 4 + 0][q * 4]);
      float4 a1 = *((const float4*)&g[grp * 4 + 1][q * 4]);
      float4 a2 = *((const float4*)&g[grp * 4 + 2][q * 4]);
      float4 a3 = *((const float4*)&g[grp * 4 + 3][q * 4]);
      float w0 = w[q * 4 + 0], w1 = w[q * 4 + 1], w2 = w[q * 4 + 2], w3 = w[q * 4 + 3];
      acc0 += w0 * a0.x + w1 * a0.y + w2 * a0.z + w3 * a0.w;
      acc1 += w0 * a1.x + w1 * a1.y + w2 * a1.z + w3 * a1.w;
      acc2 += w0 * a2.x + w1 * a2.y + w2 * a2.z + w3 * a2.w;
      acc3 += w0 * a3.x + w1 * a3.y + w2 * a3.z + w3 * a3.w;
    }
    s1 += acc0; s2 += acc0 * acc0;
    s1 += acc1; s2 += acc1 * acc1;
    s1 += acc2; s2 += acc2 * acc2;
    s1 += acc3; s2 += acc3 * acc3;
  }
  red[tid] = s1;
  __syncthreads();
  float t1 = s1 + ((grp == 0) ? red[tid + 128] : 0.f);
  __syncthreads();
  red[tid] = s2;
  __syncthreads();
  float t2 = s2 + ((grp == 0) ? red[tid + 128] : 0.f);
  if (grp == 0) {
    part[blockIdx.x * 256 + o] = t1;
    part[blockIdx.x * 256 + 128 + o] = t2;
  }
}

// ---------------- Kernel 4: reduce partials -> scale/shift per channel ----------------
__global__ __launch_bounds__(256) void bn_reduce_kernel(const float* __restrict__ part,
                                                        const float* __restrict__ gamma,
                                                        const float* __restrict__ beta,
                                                        float* __restrict__ stats) {
  const int o = blockIdx.x;  // 128
  const int tid = threadIdx.x;
  float s1 = 0.f, s2 = 0.f;
  for (int p = tid; p < 2048; p += 256) {
    s1 += part[p * 256 + o];
    s2 += part[p * 256 + 128 + o];
  }
  __shared__ float r1[256], r2[256];
  r1[tid] = s1; r2[tid] = s2;
  __syncthreads();
  for (int s = 128; s >= 1; s >>= 1) {
    if (tid < s) { r1[tid] += r1[tid + s]; r2[tid] += r2[tid + s]; }
    __syncthreads();
  }
  if (tid == 0) {
    const float n = (float)(NBATCH * NPOINT * KNN_K);
    float mean = r1[0] / n;
    float var = r2[0] / n - mean * mean;
    float inv = rsqrtf(var + 1e-5f);
    float sc = gamma[o] * inv;
    stats[o] = sc;
    stats[128 + o] = beta[o] - mean * sc;
  }
}

// ---------------- Kernel 5: recompute GEMM + BN + ReLU + max over K ----------------
// grid 8192, block 256: two centroids per block.
__global__ __launch_bounds__(256) void pool_kernel(const float* __restrict__ feat,
                                                   const float* __restrict__ W,
                                                   const int* __restrict__ knn,
                                                   const float* __restrict__ stats,
                                                   float* __restrict__ out_feat) {
  const int tid = threadIdx.x;
  const int o = tid & 127;
  const int grp = tid >> 7;
  const int pt0 = blockIdx.x * 2;
  float w[64];
  {
    const float4* wv = (const float4*)(W + (size_t)o * CIN);
#pragma unroll
    for (int q = 0; q < 16; ++q) {
      float4 v = wv[q];
      w[q * 4 + 0] = v.x; w[q * 4 + 1] = v.y; w[q * 4 + 2] = v.z; w[q * 4 + 3] = v.w;
    }
  }
  const float sc = stats[o];
  const float sh = stats[128 + o];
  __shared__ __align__(16) float g[32][CIN];
#pragma unroll
  for (int v = tid; v < 512; v += 256) {
    int row = v >> 4;        // 0..31
    int ptl = row >> 4;      // 0..1
    int k = row & 15;
    int p = pt0 + ptl;
    int r = p * KNN_K + k;
    int pidx = knn[r];
    int bb = p >> 11;
    const float4* src = (const float4*)(feat + (size_t)(bb * NPTS + pidx) * CIN);
    *((float4*)&g[row][(v & 15) * 4]) = src[v & 15];
  }
  __syncthreads();
  float mxv = -3.0e38f;
#pragma unroll
  for (int k = 0; k < KNN_K; ++k) {
    const int row = grp * 16 + k;
    float acc = 0.f;
#pragma unroll
    for (int q = 0; q < 16; ++q) {
      float4 a = *((const float4*)&g[row][q * 4]);
      acc += w[q * 4 + 0] * a.x + w[q * 4 + 1] * a.y + w[q * 4 + 2] * a.z + w[q * 4 + 3] * a.w;
    }
    float h = acc * sc + sh;
    h = fmaxf(h, 0.f);
    mxv = fmaxf(mxv, h);
  }
  out_feat[(size_t)(pt0 + grp) * COUT + o] = mxv;
}

extern "C" void kernel_launch(void* const* d_in, const int* in_sizes, int n_in,
                              void* d_out, int out_size, void* d_ws, size_t ws_size,
                              hipStream_t stream) {
  const float* xyz = (const float*)d_in[0];
  const float* feat = (const float*)d_in[1];
  const float* W = (const float*)d_in[2];
  const float* gamma = (const float*)d_in[3];
  const float* beta = (const float*)d_in[4];
  float* out = (float*)d_out;

  int* cent = (int*)d_ws;                               // 8*2048 ints
  int* knn = cent + NBATCH * NPOINT;                    // 8*2048*16 ints
  float* part = (float*)(knn + NBATCH * NPOINT * KNN_K);  // 2048*256 floats
  float* stats = part + 2048 * 256;                     // 256 floats

  float* out_xyz = out;                                 // [8,2048,3]
  float* out_feat = out + NBATCH * NPOINT * 3;          // [8,2048,128]

  hipLaunchKernelGGL(fps_kernel, dim3(NBATCH), dim3(512), 0, stream, xyz, cent);
  hipLaunchKernelGGL(knn_kernel, dim3(NBATCH * NPOINT), dim3(256), 0, stream,
                     xyz, cent, knn, out_xyz);
  hipLaunchKernelGGL(gemm_stats_kernel, dim3(2048), dim3(256), 0, stream,
                     feat, W, knn, part);
  hipLaunchKernelGGL(bn_reduce_kernel, dim3(128), dim3(256), 0, stream,
                     part, gamma, beta, stats);
  hipLaunchKernelGGL(pool_kernel, dim3(8192), dim3(256), 0, stream,
                     feat, W, knn, stats, out_feat);
}

// Round 2
// 2723.469 us; speedup vs baseline: 1.2042x; 1.2042x over previous
//
#include <hip/hip_runtime.h>
#include <stdint.h>

#define NPTS 8192
#define NBATCH 8
#define NPOINT 2048
#define KNN_K 16
#define CIN 64
#define COUT 128

typedef unsigned long long u64;
typedef unsigned int u32;

// ---------------- Kernel 1: farthest point sampling ----------------
// grid NBATCH, block 512. 16 points/thread in registers; full point cloud
// mirrored into LDS (SoA, 96KB) so every thread can read the new centroid's
// coords by index with a broadcast ds_read (no second barrier, no publish).
__global__ __launch_bounds__(512) void fps_kernel(const float* __restrict__ xyz,
                                                  int* __restrict__ cent) {
  const int b = blockIdx.x;
  const int tid = threadIdx.x;
  const float* xb = xyz + (size_t)b * NPTS * 3;
  __shared__ float xs[NPTS];
  __shared__ float ys[NPTS];
  __shared__ float zs[NPTS];
  __shared__ u64 kbuf[2][8];

  float px[16], py[16], pz[16], dist[16];
#pragma unroll
  for (int j = 0; j < 16; ++j) {
    int i = tid + 512 * j;
    float x = xb[i * 3 + 0], y = xb[i * 3 + 1], z = xb[i * 3 + 2];
    px[j] = x; py[j] = y; pz[j] = z;
    dist[j] = 1e10f;
    xs[i] = x; ys[i] = y; zs[i] = z;
  }
  if (tid == 0) cent[b * NPOINT] = 0;
  __syncthreads();
  float cx = xs[0], cy = ys[0], cz = zs[0];
  const int lane = tid & 63;
  const int wid = tid >> 6;  // 8 waves

  for (int it = 1; it < NPOINT; ++it) {
    float nd[16];
#pragma unroll
    for (int j = 0; j < 16; ++j) {
      float dx = px[j] - cx, dy = py[j] - cy, dz = pz[j] - cz;
      float dd = dx * dx + dy * dy + dz * dz;   // same expr as round 1 (passed)
      float t = fminf(dist[j], dd);
      dist[j] = t;
      nd[j] = t;
    }
    // tree max (depth 4), then first-index scan for the tie-break
    float tr[16];
#pragma unroll
    for (int j = 0; j < 16; ++j) tr[j] = nd[j];
#pragma unroll
    for (int s = 1; s < 16; s <<= 1) {
#pragma unroll
      for (int j = 0; j < 16; j += 2 * s) tr[j] = fmaxf(tr[j], tr[j + s]);
    }
    float bv = tr[0];
    int bj = 0;
#pragma unroll
    for (int j = 15; j >= 1; --j) {
      if (nd[j] == bv) bj = j;  // descending: smallest matching j wins
    }
    u32 idx = (u32)(tid + (bj << 9));
    // max-key: larger distance wins; equal distance -> smaller index wins
    u64 key = ((u64)__float_as_uint(bv) << 32) | (u64)(0xFFFFFFFFu - idx);
#pragma unroll
    for (int off = 32; off >= 1; off >>= 1) {
      u64 other = __shfl_xor(key, off, 64);
      key = (other > key) ? other : key;
    }
    if (lane == 0) kbuf[it & 1][wid] = key;
    __syncthreads();  // the only barrier per iteration
    u64 k2 = kbuf[it & 1][lane & 7];
#pragma unroll
    for (int off = 4; off >= 1; off >>= 1) {
      u64 other = __shfl_xor(k2, off, 64);
      k2 = (other > k2) ? other : k2;
    }
    u32 widx = 0xFFFFFFFFu - (u32)(k2 & 0xFFFFFFFFu);
    if (tid == 0) cent[b * NPOINT + it] = (int)widx;
    cx = xs[widx]; cy = ys[widx]; cz = zs[widx];  // broadcast LDS read
  }
}

// ---------------- Kernel 2: 16-NN per centroid + new_xyz gather ----------------
// grid NBATCH*NPOINT, block 256. 32 candidate dists per thread in registers.
__global__ __launch_bounds__(256) void knn_kernel(const float* __restrict__ xyz,
                                                  const int* __restrict__ cent,
                                                  int* __restrict__ knn,
                                                  float* __restrict__ out_xyz) {
  const int pt = blockIdx.x;       // 0..16383
  const int b = pt >> 11;
  const int tid = threadIdx.x;
  const float* xb = xyz + (size_t)b * NPTS * 3;
  const int ci = cent[pt];
  const float mx = xb[ci * 3 + 0], my = xb[ci * 3 + 1], mz = xb[ci * 3 + 2];
  if (tid < 3) out_xyz[pt * 3 + tid] = xb[ci * 3 + tid];
  const float sm = mx * mx + my * my + mz * mz;

  float d[32];
  float lv = 3.0e38f;
  int lj = 0;
#pragma unroll
  for (int j = 0; j < 32; ++j) {
    int i = tid + 256 * j;
    float x = xb[i * 3 + 0], y = xb[i * 3 + 1], z = xb[i * 3 + 2];
    float dot = mx * x + my * y + mz * z;
    float sp = x * x + y * y + z * z;
    float dd = -2.0f * dot + sm + sp;   // same assoc as reference
    d[j] = dd;
    if (dd < lv) { lv = dd; lj = j; }
  }

  __shared__ u64 kbuf[2][4];
  const int lane = tid & 63;
  const int wid = tid >> 6;  // 4 waves

  for (int p = 0; p < KNN_K; ++p) {
    u32 fb = __float_as_uint(lv);
    u32 mapped = (fb & 0x80000000u) ? ~fb : (fb | 0x80000000u);  // order-preserving
    u32 idx = (u32)(tid + (lj << 8));  // == point index
    u64 key = ((u64)mapped << 32) | (u64)idx;  // min-key: smaller d, then smaller idx
#pragma unroll
    for (int off = 32; off >= 1; off >>= 1) {
      u64 other = __shfl_xor(key, off, 64);
      key = (other < key) ? other : key;
    }
    if (lane == 0) kbuf[p & 1][wid] = key;
    __syncthreads();
    u64 k2 = kbuf[p & 1][lane & 3];
#pragma unroll
    for (int off = 2; off >= 1; off >>= 1) {
      u64 other = __shfl_xor(k2, off, 64);
      k2 = (other < k2) ? other : k2;
    }
    u32 widx = (u32)(k2 & 0xFFFFFFFFu);
    if (tid == 0) knn[pt * KNN_K + p] = (int)widx;
    if (tid == (int)(widx & 255u)) {
      int j0 = (int)(widx >> 8);
      float nlv = 3.0e38f;
      int nlj = 0;
#pragma unroll
      for (int j = 0; j < 32; ++j) {
        if (j == j0) d[j] = 3.0e38f;
        if (d[j] < nlv) { nlv = d[j]; nlj = j; }
      }
      lv = nlv; lj = nlj;
    }
  }
}

// ---------------- Kernel 3: gather+GEMM + BN partials + per-(pt,o) max/min ----------------
// grid 2048, block 256: 8 centroids (128 rows) per block, staged once in LDS.
// Thread = (grp 0..3, opair 0..63): 2 output channels, 2 centroids.
// Writes per-(pt,o) raw max -> out_feat, min -> mnbuf; BN partials -> part.
__global__ __launch_bounds__(256) void gemm_stats_kernel(const float* __restrict__ feat,
                                                         const float* __restrict__ W,
                                                         const int* __restrict__ knn,
                                                         float* __restrict__ part,
                                                         float* __restrict__ mxbuf,
                                                         float* __restrict__ mnbuf) {
  const int tid = threadIdx.x;
  const int o0 = (tid & 63) * 2;
  const int o1 = o0 + 1;
  const int grp = tid >> 6;  // wave id, 0..3
  __shared__ __align__(16) float g[128][CIN];
  __shared__ int kidx[128];
  __shared__ float sred[4][128];

  const int rowbase = blockIdx.x * 128;
  if (tid < 128) kidx[tid] = knn[rowbase + tid];

  float4 w0v[16], w1v[16];
  {
    const float4* wv0 = (const float4*)(W + (size_t)o0 * CIN);
    const float4* wv1 = (const float4*)(W + (size_t)o1 * CIN);
#pragma unroll
    for (int q = 0; q < 16; ++q) { w0v[q] = wv0[q]; w1v[q] = wv1[q]; }
  }
  __syncthreads();
  // stage all 128 gathered rows
#pragma unroll
  for (int s = 0; s < 8; ++s) {
    int v = tid + 256 * s;
    int row = v >> 4, q = v & 15;
    int gr = rowbase + row;
    int bb = gr >> 15;  // 32768 rows per batch
    const float4* src = (const float4*)(feat + (size_t)(bb * NPTS + kidx[row]) * CIN);
    *((float4*)&g[row][q * 4]) = src[q];
  }
  __syncthreads();

  float s1_0 = 0.f, s2_0 = 0.f, s1_1 = 0.f, s2_1 = 0.f;
#pragma unroll
  for (int pp = 0; pp < 2; ++pp) {
    const int ptl = grp + pp * 4;  // 0..7
    float mx0 = -3.0e38f, mn0 = 3.0e38f, mx1 = -3.0e38f, mn1 = 3.0e38f;
#pragma unroll
    for (int k = 0; k < KNN_K; ++k) {
      const int row = ptl * 16 + k;
      float a0 = 0.f, a1 = 0.f;
#pragma unroll
      for (int q = 0; q < 16; ++q) {
        float4 a = *((const float4*)&g[row][q * 4]);  // broadcast within wave
        a0 += w0v[q].x * a.x + w0v[q].y * a.y + w0v[q].z * a.z + w0v[q].w * a.w;
        a1 += w1v[q].x * a.x + w1v[q].y * a.y + w1v[q].z * a.z + w1v[q].w * a.w;
      }
      s1_0 += a0; s2_0 += a0 * a0; mx0 = fmaxf(mx0, a0); mn0 = fminf(mn0, a0);
      s1_1 += a1; s2_1 += a1 * a1; mx1 = fmaxf(mx1, a1); mn1 = fminf(mn1, a1);
    }
    const size_t pt = (size_t)blockIdx.x * 8 + ptl;
    mxbuf[pt * COUT + o0] = mx0;
    mxbuf[pt * COUT + o1] = mx1;
    mnbuf[pt * COUT + o0] = mn0;
    mnbuf[pt * COUT + o1] = mn1;
  }
  // block-reduce BN partials across the 4 waves
  sred[grp][o0] = s1_0; sred[grp][o1] = s1_1;
  __syncthreads();
  if (tid < 128) {
    float t = sred[0][tid] + sred[1][tid] + sred[2][tid] + sred[3][tid];
    part[blockIdx.x * 256 + tid] = t;
  }
  __syncthreads();
  sred[grp][o0] = s2_0; sred[grp][o1] = s2_1;
  __syncthreads();
  if (tid < 128) {
    float t = sred[0][tid] + sred[1][tid] + sred[2][tid] + sred[3][tid];
    part[blockIdx.x * 256 + 128 + tid] = t;
  }
}

// ---------------- Kernel 4: reduce partials -> scale/shift per channel ----------------
__global__ __launch_bounds__(256) void bn_reduce_kernel(const float* __restrict__ part,
                                                        const float* __restrict__ gamma,
                                                        const float* __restrict__ beta,
                                                        float* __restrict__ stats) {
  const int o = blockIdx.x;  // 128
  const int tid = threadIdx.x;
  float s1 = 0.f, s2 = 0.f;
  for (int p = tid; p < 2048; p += 256) {
    s1 += part[p * 256 + o];
    s2 += part[p * 256 + 128 + o];
  }
  __shared__ float r1[256], r2[256];
  r1[tid] = s1; r2[tid] = s2;
  __syncthreads();
  for (int s = 128; s >= 1; s >>= 1) {
    if (tid < s) { r1[tid] += r1[tid + s]; r2[tid] += r2[tid + s]; }
    __syncthreads();
  }
  if (tid == 0) {
    const float n = (float)(NBATCH * NPOINT * KNN_K);
    float mean = r1[0] / n;
    float var = r2[0] / n - mean * mean;
    float inv = rsqrtf(var + 1e-5f);
    float sc = gamma[o] * inv;
    stats[o] = sc;
    stats[128 + o] = beta[o] - mean * sc;
  }
}

// ---------------- Kernel 5: finalize out = relu(sel*sc + sh) ----------------
// max_k relu(a*sc+sh) == relu((sc>=0 ? max_k a : min_k a)*sc + sh)
__global__ __launch_bounds__(256) void finalize_kernel(float* __restrict__ out_feat,
                                                       const float* __restrict__ mnbuf,
                                                       const float* __restrict__ stats) {
  const int i = blockIdx.x * 256 + threadIdx.x;  // 16384*128 total
  const int o = i & 127;
  const float sc = stats[o];
  const float sh = stats[128 + o];
  const float mx = out_feat[i];
  const float mn = mnbuf[i];
  const float sel = (sc >= 0.f) ? mx : mn;
  out_feat[i] = fmaxf(sel * sc + sh, 0.f);
}

extern "C" void kernel_launch(void* const* d_in, const int* in_sizes, int n_in,
                              void* d_out, int out_size, void* d_ws, size_t ws_size,
                              hipStream_t stream) {
  const float* xyz = (const float*)d_in[0];
  const float* feat = (const float*)d_in[1];
  const float* W = (const float*)d_in[2];
  const float* gamma = (const float*)d_in[3];
  const float* beta = (const float*)d_in[4];
  float* out = (float*)d_out;

  int* cent = (int*)d_ws;                                  // 16384 ints
  int* knn = cent + NBATCH * NPOINT;                       // 262144 ints
  float* part = (float*)(knn + NBATCH * NPOINT * KNN_K);   // 2048*256 f32
  float* stats = part + 2048 * 256;                        // 256 f32
  float* mnbuf = stats + 256;                              // 16384*128 f32

  float* out_xyz = out;                                    // [8,2048,3]
  float* out_feat = out + NBATCH * NPOINT * 3;             // [8,2048,128]

  hipLaunchKernelGGL(fps_kernel, dim3(NBATCH), dim3(512), 0, stream, xyz, cent);
  hipLaunchKernelGGL(knn_kernel, dim3(NBATCH * NPOINT), dim3(256), 0, stream,
                     xyz, cent, knn, out_xyz);
  hipLaunchKernelGGL(gemm_stats_kernel, dim3(2048), dim3(256), 0, stream,
                     feat, W, knn, part, out_feat, mnbuf);
  hipLaunchKernelGGL(bn_reduce_kernel, dim3(128), dim3(256), 0, stream,
                     part, gamma, beta, stats);
  hipLaunchKernelGGL(finalize_kernel, dim3(8192), dim3(256), 0, stream,
                     out_feat, mnbuf, stats);
}

// Round 4
// 2046.851 us; speedup vs baseline: 1.6022x; 1.3306x over previous
//
#include <hip/hip_runtime.h>
#include <stdint.h>

#define NPTS 8192
#define NBATCH 8
#define NPOINT 2048
#define KNN_K 16
#define CIN 64
#define COUT 128

typedef unsigned long long u64;
typedef unsigned int u32;

#define MAXU64(a, b) (((a) > (b)) ? (a) : (b))
#define MAXF64(a, b) fmax((a), (b))

// wave64 max-reduce of a positive-finite f64 key via DPP row_shr + row_bcast.
// Classic GPUOpen sequence: row_shr 1/2/4/8 accumulates at lane 15 of each row,
// row_bcast15 -> lane 31/63 combine, row_bcast31 -> lane 63 holds full max.
// bound_ctrl=true injects 0.0, harmless for max over keys > 0.
__device__ __forceinline__ double wave_max_f64(double v) {
#define DPPSTEP(C)                                                             \
  {                                                                            \
    u64 k = (u64)__double_as_longlong(v);                                      \
    u32 lo = (u32)k, hi = (u32)(k >> 32);                                      \
    u32 nlo = (u32)__builtin_amdgcn_update_dpp(0, (int)lo, C, 0xf, 0xf, true); \
    u32 nhi = (u32)__builtin_amdgcn_update_dpp(0, (int)hi, C, 0xf, 0xf, true); \
    double o = __longlong_as_double((long long)(((u64)nhi << 32) | nlo));      \
    v = fmax(v, o);                                                            \
  }
  DPPSTEP(0x111)  // row_shr:1
  DPPSTEP(0x112)  // row_shr:2
  DPPSTEP(0x114)  // row_shr:4
  DPPSTEP(0x118)  // row_shr:8  -> lane 15+16r = row max
  DPPSTEP(0x142)  // row_bcast15 -> lane 31 = rows0-1, lane 63 = rows2-3
  DPPSTEP(0x143)  // row_bcast31 -> lane 63 = all
#undef DPPSTEP
  return v;
}

// wave64 max-reduce on exact u64 keys (same shape, cmp+select combine).
__device__ __forceinline__ u64 wave_max_u64(u64 k) {
  u32 lo = (u32)k, hi = (u32)(k >> 32);
#define DPPSTEP(C)                                                             \
  {                                                                            \
    u32 nlo = (u32)__builtin_amdgcn_update_dpp(0, (int)lo, C, 0xf, 0xf, true); \
    u32 nhi = (u32)__builtin_amdgcn_update_dpp(0, (int)hi, C, 0xf, 0xf, true); \
    u64 cur = ((u64)hi << 32) | lo;                                            \
    u64 oth = ((u64)nhi << 32) | nlo;                                          \
    if (oth > cur) { hi = nhi; lo = nlo; }                                     \
  }
  DPPSTEP(0x111)  // row_shr:1
  DPPSTEP(0x112)  // row_shr:2
  DPPSTEP(0x114)  // row_shr:4
  DPPSTEP(0x118)  // row_shr:8
  DPPSTEP(0x142)  // row_bcast15
  DPPSTEP(0x143)  // row_bcast31
#undef DPPSTEP
  return ((u64)hi << 32) | lo;
}

// ---------------- Kernel 1: farthest point sampling ----------------
// grid NBATCH, block 512. 16 points/thread in registers; cloud mirrored in
// LDS (SoA) for the centroid coord broadcast. Key = (dist_bits<<32)|~pointidx
// treated as positive f64: max == larger dist, tie -> smaller point index.
__global__ __launch_bounds__(512) void fps_kernel(const float* __restrict__ xyz,
                                                  int* __restrict__ cent) {
  const int b = blockIdx.x;
  const int tid = threadIdx.x;
  const float* xb = xyz + (size_t)b * NPTS * 3;
  __shared__ float xs[NPTS];
  __shared__ float ys[NPTS];
  __shared__ float zs[NPTS];
  __shared__ __align__(16) double kbuf[2][8];

  float px[16], py[16], pz[16], dist[16];
  u32 klo[16];
#pragma unroll
  for (int j = 0; j < 16; ++j) {
    int i = tid + 512 * j;
    float x = xb[i * 3 + 0], y = xb[i * 3 + 1], z = xb[i * 3 + 2];
    px[j] = x; py[j] = y; pz[j] = z;
    dist[j] = 1e10f;
    xs[i] = x; ys[i] = y; zs[i] = z;
    klo[j] = ~(u32)i;  // larger klo == smaller point index
  }
  if (tid == 0) cent[b * NPOINT] = 0;
  __syncthreads();
  float cx = xs[0], cy = ys[0], cz = zs[0];
  const int lane = tid & 63;
  const int wid = tid >> 6;  // 8 waves

  for (int it = 1; it < NPOINT; ++it) {
    double key[16];
#pragma unroll
    for (int j = 0; j < 16; ++j) {
      float dx = px[j] - cx, dy = py[j] - cy, dz = pz[j] - cz;
      float dd = dx * dx + dy * dy + dz * dz;   // same expr as rounds 1-2
      float t = fminf(dist[j], dd);
      dist[j] = t;
      key[j] = __longlong_as_double(
          (long long)(((u64)__float_as_uint(t) << 32) | klo[j]));
    }
    // local 16 -> 1: depth-4 tree of v_max_f64 (exact: keys are positive f64)
#pragma unroll
    for (int s = 1; s < 16; s <<= 1) {
#pragma unroll
      for (int j = 0; j < 16; j += 2 * s) key[j] = MAXF64(key[j], key[j + s]);
    }
    // wave 64 -> 1 on VALU (DPP); lane 63 owns the result
    double wk = wave_max_f64(key[0]);
    if (lane == 63) kbuf[it & 1][wid] = wk;
    __syncthreads();  // the only barrier per iteration
    // every thread redundantly resolves the block winner: 4 b128 broadcasts
    const double2* kb = (const double2*)&kbuf[it & 1][0];
    double2 p0 = kb[0], p1 = kb[1], p2 = kb[2], p3 = kb[3];
    double m0 = MAXF64(p0.x, p0.y), m1 = MAXF64(p1.x, p1.y);
    double m2 = MAXF64(p2.x, p2.y), m3 = MAXF64(p3.x, p3.y);
    double best = MAXF64(MAXF64(m0, m1), MAXF64(m2, m3));
    u32 widx = ~(u32)(u64)__double_as_longlong(best);  // winner point index
    if (tid == 0) cent[b * NPOINT + it] = (int)widx;
    cx = xs[widx]; cy = ys[widx]; cz = zs[widx];  // broadcast LDS reads
  }
}

// ---------------- Kernel 2: 16-NN per centroid + new_xyz gather ----------------
// grid NBATCH*NPOINT, block 256. 32 candidate dists per thread in registers.
// Min-extraction via inverted keys + exact u64 DPP max-reduce.
__global__ __launch_bounds__(256) void knn_kernel(const float* __restrict__ xyz,
                                                  const int* __restrict__ cent,
                                                  int* __restrict__ knn,
                                                  float* __restrict__ out_xyz) {
  const int pt = blockIdx.x;       // 0..16383
  const int b = pt >> 11;
  const int tid = threadIdx.x;
  const float* xb = xyz + (size_t)b * NPTS * 3;
  const int ci = cent[pt];
  const float mx = xb[ci * 3 + 0], my = xb[ci * 3 + 1], mz = xb[ci * 3 + 2];
  if (tid < 3) out_xyz[pt * 3 + tid] = xb[ci * 3 + tid];
  const float sm = mx * mx + my * my + mz * mz;

  float d[32];
  float lv = 3.0e38f;
  int lj = 0;
#pragma unroll
  for (int j = 0; j < 32; ++j) {
    int i = tid + 256 * j;
    float x = xb[i * 3 + 0], y = xb[i * 3 + 1], z = xb[i * 3 + 2];
    float dot = mx * x + my * y + mz * z;
    float sp = x * x + y * y + z * z;
    float dd = -2.0f * dot + sm + sp;   // same assoc as reference
    d[j] = dd;
    if (dd < lv) { lv = dd; lj = j; }
  }

  __shared__ __align__(16) u64 kbuf[2][4];
  const int lane = tid & 63;

  for (int p = 0; p < KNN_K; ++p) {
    u32 fb = __float_as_uint(lv);
    u32 mapped = (fb & 0x80000000u) ? ~fb : (fb | 0x80000000u);  // order-preserving
    u32 idx = (u32)(tid + (lj << 8));  // == point index
    // min-key (smaller d, then smaller idx) == max of inverted key
    u64 ik = ~(((u64)mapped << 32) | (u64)idx);
    u64 wk = wave_max_u64(ik);
    if (lane == 63) kbuf[p & 1][tid >> 6] = wk;
    __syncthreads();
    const ulonglong2* kb = (const ulonglong2*)&kbuf[p & 1][0];
    ulonglong2 q0 = kb[0], q1 = kb[1];
    u64 best = MAXU64(MAXU64(q0.x, q0.y), MAXU64(q1.x, q1.y));
    u32 widx = (u32)(~best);  // point index of the minimum
    if (tid == 0) knn[pt * KNN_K + p] = (int)widx;
    if (tid == (int)(widx & 255u)) {
      int j0 = (int)(widx >> 8);
      float nlv = 3.0e38f;
      int nlj = 0;
#pragma unroll
      for (int j = 0; j < 32; ++j) {
        if (j == j0) d[j] = 3.0e38f;
        if (d[j] < nlv) { nlv = d[j]; nlj = j; }
      }
      lv = nlv; lj = nlj;
    }
  }
}

// ---------------- Kernel 3: gather+GEMM + BN partials + per-(pt,o) max/min ----------------
__global__ __launch_bounds__(256) void gemm_stats_kernel(const float* __restrict__ feat,
                                                         const float* __restrict__ W,
                                                         const int* __restrict__ knn,
                                                         float* __restrict__ part,
                                                         float* __restrict__ mxbuf,
                                                         float* __restrict__ mnbuf) {
  const int tid = threadIdx.x;
  const int o0 = (tid & 63) * 2;
  const int o1 = o0 + 1;
  const int grp = tid >> 6;  // wave id, 0..3
  __shared__ __align__(16) float g[128][CIN];
  __shared__ int kidx[128];
  __shared__ float sred[4][128];

  const int rowbase = blockIdx.x * 128;
  if (tid < 128) kidx[tid] = knn[rowbase + tid];

  float4 w0v[16], w1v[16];
  {
    const float4* wv0 = (const float4*)(W + (size_t)o0 * CIN);
    const float4* wv1 = (const float4*)(W + (size_t)o1 * CIN);
#pragma unroll
    for (int q = 0; q < 16; ++q) { w0v[q] = wv0[q]; w1v[q] = wv1[q]; }
  }
  __syncthreads();
#pragma unroll
  for (int s = 0; s < 8; ++s) {
    int v = tid + 256 * s;
    int row = v >> 4, q = v & 15;
    int gr = rowbase + row;
    int bb = gr >> 15;  // 32768 rows per batch
    const float4* src = (const float4*)(feat + (size_t)(bb * NPTS + kidx[row]) * CIN);
    *((float4*)&g[row][q * 4]) = src[q];
  }
  __syncthreads();

  float s1_0 = 0.f, s2_0 = 0.f, s1_1 = 0.f, s2_1 = 0.f;
#pragma unroll
  for (int pp = 0; pp < 2; ++pp) {
    const int ptl = grp + pp * 4;  // 0..7
    float mx0 = -3.0e38f, mn0 = 3.0e38f, mx1 = -3.0e38f, mn1 = 3.0e38f;
#pragma unroll
    for (int k = 0; k < KNN_K; ++k) {
      const int row = ptl * 16 + k;
      float a0 = 0.f, a1 = 0.f;
#pragma unroll
      for (int q = 0; q < 16; ++q) {
        float4 a = *((const float4*)&g[row][q * 4]);  // broadcast within wave
        a0 += w0v[q].x * a.x + w0v[q].y * a.y + w0v[q].z * a.z + w0v[q].w * a.w;
        a1 += w1v[q].x * a.x + w1v[q].y * a.y + w1v[q].z * a.z + w1v[q].w * a.w;
      }
      s1_0 += a0; s2_0 += a0 * a0; mx0 = fmaxf(mx0, a0); mn0 = fminf(mn0, a0);
      s1_1 += a1; s2_1 += a1 * a1; mx1 = fmaxf(mx1, a1); mn1 = fminf(mn1, a1);
    }
    const size_t pt = (size_t)blockIdx.x * 8 + ptl;
    mxbuf[pt * COUT + o0] = mx0;
    mxbuf[pt * COUT + o1] = mx1;
    mnbuf[pt * COUT + o0] = mn0;
    mnbuf[pt * COUT + o1] = mn1;
  }
  sred[grp][o0] = s1_0; sred[grp][o1] = s1_1;
  __syncthreads();
  if (tid < 128) {
    float t = sred[0][tid] + sred[1][tid] + sred[2][tid] + sred[3][tid];
    part[blockIdx.x * 256 + tid] = t;
  }
  __syncthreads();
  sred[grp][o0] = s2_0; sred[grp][o1] = s2_1;
  __syncthreads();
  if (tid < 128) {
    float t = sred[0][tid] + sred[1][tid] + sred[2][tid] + sred[3][tid];
    part[blockIdx.x * 256 + 128 + tid] = t;
  }
}

// ---------------- Kernel 4: reduce partials -> scale/shift per channel ----------------
__global__ __launch_bounds__(256) void bn_reduce_kernel(const float* __restrict__ part,
                                                        const float* __restrict__ gamma,
                                                        const float* __restrict__ beta,
                                                        float* __restrict__ stats) {
  const int o = blockIdx.x;  // 128
  const int tid = threadIdx.x;
  float s1 = 0.f, s2 = 0.f;
  for (int p = tid; p < 2048; p += 256) {
    s1 += part[p * 256 + o];
    s2 += part[p * 256 + 128 + o];
  }
  __shared__ float r1[256], r2[256];
  r1[tid] = s1; r2[tid] = s2;
  __syncthreads();
  for (int s = 128; s >= 1; s >>= 1) {
    if (tid < s) { r1[tid] += r1[tid + s]; r2[tid] += r2[tid + s]; }
    __syncthreads();
  }
  if (tid == 0) {
    const float n = (float)(NBATCH * NPOINT * KNN_K);
    float mean = r1[0] / n;
    float var = r2[0] / n - mean * mean;
    float inv = rsqrtf(var + 1e-5f);
    float sc = gamma[o] * inv;
    stats[o] = sc;
    stats[128 + o] = beta[o] - mean * sc;
  }
}

// ---------------- Kernel 5: finalize out = relu(sel*sc + sh) ----------------
__global__ __launch_bounds__(256) void finalize_kernel(float* __restrict__ out_feat,
                                                       const float* __restrict__ mnbuf,
                                                       const float* __restrict__ stats) {
  const int i = blockIdx.x * 256 + threadIdx.x;  // 16384*128 total
  const int o = i & 127;
  const float sc = stats[o];
  const float sh = stats[128 + o];
  const float mx = out_feat[i];
  const float mn = mnbuf[i];
  const float sel = (sc >= 0.f) ? mx : mn;
  out_feat[i] = fmaxf(sel * sc + sh, 0.f);
}

extern "C" void kernel_launch(void* const* d_in, const int* in_sizes, int n_in,
                              void* d_out, int out_size, void* d_ws, size_t ws_size,
                              hipStream_t stream) {
  const float* xyz = (const float*)d_in[0];
  const float* feat = (const float*)d_in[1];
  const float* W = (const float*)d_in[2];
  const float* gamma = (const float*)d_in[3];
  const float* beta = (const float*)d_in[4];
  float* out = (float*)d_out;

  int* cent = (int*)d_ws;                                  // 16384 ints
  int* knn = cent + NBATCH * NPOINT;                       // 262144 ints
  float* part = (float*)(knn + NBATCH * NPOINT * KNN_K);   // 2048*256 f32
  float* stats = part + 2048 * 256;                        // 256 f32
  float* mnbuf = stats + 256;                              // 16384*128 f32

  float* out_xyz = out;                                    // [8,2048,3]
  float* out_feat = out + NBATCH * NPOINT * 3;             // [8,2048,128]

  hipLaunchKernelGGL(fps_kernel, dim3(NBATCH), dim3(512), 0, stream, xyz, cent);
  hipLaunchKernelGGL(knn_kernel, dim3(NBATCH * NPOINT), dim3(256), 0, stream,
                     xyz, cent, knn, out_xyz);
  hipLaunchKernelGGL(gemm_stats_kernel, dim3(2048), dim3(256), 0, stream,
                     feat, W, knn, part, out_feat, mnbuf);
  hipLaunchKernelGGL(bn_reduce_kernel, dim3(128), dim3(256), 0, stream,
                     part, gamma, beta, stats);
  hipLaunchKernelGGL(finalize_kernel, dim3(8192), dim3(256), 0, stream,
                     out_feat, mnbuf, stats);
}

// Round 5
// 2002.361 us; speedup vs baseline: 1.6378x; 1.0222x over previous
//
#include <hip/hip_runtime.h>
#include <stdint.h>

#define NPTS 8192
#define NBATCH 8
#define NPOINT 2048
#define KNN_K 16
#define CIN 64
#define COUT 128

typedef unsigned long long u64;
typedef unsigned int u32;

#define MAXU64(a, b) (((a) > (b)) ? (a) : (b))
#define MAXF64(a, b) fmax((a), (b))

// wave64 max-reduce of a positive-finite f64 key via DPP row_shr + row_bcast.
// row_shr 1/2/4/8 accumulates at lane 15 of each row, row_bcast15 -> lane
// 31/63, row_bcast31 -> lane 63 holds the full-wave max. bound_ctrl=true
// injects 0.0, harmless for max over keys > 0.
__device__ __forceinline__ double wave_max_f64(double v) {
#define DPPSTEP(C)                                                             \
  {                                                                            \
    u64 k = (u64)__double_as_longlong(v);                                      \
    u32 lo = (u32)k, hi = (u32)(k >> 32);                                      \
    u32 nlo = (u32)__builtin_amdgcn_update_dpp(0, (int)lo, C, 0xf, 0xf, true); \
    u32 nhi = (u32)__builtin_amdgcn_update_dpp(0, (int)hi, C, 0xf, 0xf, true); \
    double o = __longlong_as_double((long long)(((u64)nhi << 32) | nlo));      \
    v = fmax(v, o);                                                            \
  }
  DPPSTEP(0x111)  // row_shr:1
  DPPSTEP(0x112)  // row_shr:2
  DPPSTEP(0x114)  // row_shr:4
  DPPSTEP(0x118)  // row_shr:8  -> lane 15+16r = row max
  DPPSTEP(0x142)  // row_bcast15 -> lane 31 / lane 63
  DPPSTEP(0x143)  // row_bcast31 -> lane 63 = all
#undef DPPSTEP
  return v;
}

// wave64 max-reduce on exact u64 keys (same shape, cmp+select combine).
__device__ __forceinline__ u64 wave_max_u64(u64 k) {
  u32 lo = (u32)k, hi = (u32)(k >> 32);
#define DPPSTEP(C)                                                             \
  {                                                                            \
    u32 nlo = (u32)__builtin_amdgcn_update_dpp(0, (int)lo, C, 0xf, 0xf, true); \
    u32 nhi = (u32)__builtin_amdgcn_update_dpp(0, (int)hi, C, 0xf, 0xf, true); \
    u64 cur = ((u64)hi << 32) | lo;                                            \
    u64 oth = ((u64)nhi << 32) | nlo;                                          \
    if (oth > cur) { hi = nhi; lo = nlo; }                                     \
  }
  DPPSTEP(0x111)
  DPPSTEP(0x112)
  DPPSTEP(0x114)
  DPPSTEP(0x118)
  DPPSTEP(0x142)
  DPPSTEP(0x143)
#undef DPPSTEP
  return ((u64)hi << 32) | lo;
}

// ---------------- Kernel 1: farthest point sampling with exact wave pruning --
// grid NBATCH, block 512 (8 waves). One-time: counting-sort points by octant
// so each wave owns a spatially coherent 1024-point bucket; compute the
// bucket's true bbox. Per iteration: if dist^2(centroid, bbox) exceeds the
// wave's current max dist (with rounding margin), the whole min-update is
// provably a no-op -> wave re-posts its previous key (bit-exact skip).
__global__ __launch_bounds__(512) void fps_kernel(const float* __restrict__ xyz,
                                                  int* __restrict__ cent) {
  const int b = blockIdx.x;
  const int tid = threadIdx.x;
  const float* xb = xyz + (size_t)b * NPTS * 3;
  __shared__ float xs[NPTS];
  __shared__ float ys[NPTS];
  __shared__ float zs[NPTS];
  __shared__ unsigned short sorted[NPTS];
  __shared__ int cnt8[8], base8[8], cur8[8];
  __shared__ float bbox[8][6];         // xlo,xhi,ylo,yhi,zlo,zhi per wave
  __shared__ float scratch[512][6];    // per-thread local bbox
  __shared__ __align__(16) double kbuf[2][8];

  if (tid < 8) { cnt8[tid] = 0; cur8[tid] = 0; }

  float lx[16], ly[16], lz[16];
#pragma unroll
  for (int j = 0; j < 16; ++j) {
    int i = tid + 512 * j;
    lx[j] = xb[i * 3 + 0];
    ly[j] = xb[i * 3 + 1];
    lz[j] = xb[i * 3 + 2];
  }
  __syncthreads();  // cnt8 init visible
#pragma unroll
  for (int j = 0; j < 16; ++j) {
    int i = tid + 512 * j;
    xs[i] = lx[j]; ys[i] = ly[j]; zs[i] = lz[j];
    int oct = ((lx[j] > 0.f) ? 4 : 0) | ((ly[j] > 0.f) ? 2 : 0) | ((lz[j] > 0.f) ? 1 : 0);
    atomicAdd(&cnt8[oct], 1);
  }
  __syncthreads();
  if (tid == 0) {
    int acc = 0;
#pragma unroll
    for (int o = 0; o < 8; ++o) { base8[o] = acc; acc += cnt8[o]; }
  }
  __syncthreads();
#pragma unroll
  for (int j = 0; j < 16; ++j) {
    int i = tid + 512 * j;
    int oct = ((lx[j] > 0.f) ? 4 : 0) | ((ly[j] > 0.f) ? 2 : 0) | ((lz[j] > 0.f) ? 1 : 0);
    int pos = base8[oct] + atomicAdd(&cur8[oct], 1);
    sorted[pos] = (unsigned short)i;
  }
  if (tid == 0) cent[b * NPOINT] = 0;
  __syncthreads();

  const int lane = tid & 63;
  const int wid = tid >> 6;  // 8 waves == 8 buckets

  // load this wave's 1024-point bucket (16/thread) + local bbox
  float px[16], py[16], pz[16], dist[16];
  u32 klo[16];
  float xl = 3e38f, xh = -3e38f, yl = 3e38f, yh = -3e38f, zl = 3e38f, zh = -3e38f;
#pragma unroll
  for (int j = 0; j < 16; ++j) {
    int pi = (int)sorted[wid * 1024 + lane + 64 * j];
    float x = xs[pi], y = ys[pi], z = zs[pi];
    px[j] = x; py[j] = y; pz[j] = z;
    dist[j] = 1e10f;
    klo[j] = ~(u32)pi;  // larger klo == smaller point index
    xl = fminf(xl, x); xh = fmaxf(xh, x);
    yl = fminf(yl, y); yh = fmaxf(yh, y);
    zl = fminf(zl, z); zh = fmaxf(zh, z);
  }
  scratch[tid][0] = xl; scratch[tid][1] = xh;
  scratch[tid][2] = yl; scratch[tid][3] = yh;
  scratch[tid][4] = zl; scratch[tid][5] = zh;
  __syncthreads();
  if (tid < 48) {
    int w = tid / 6, q = tid % 6;
    float v = scratch[w * 64][q];
    if (q & 1) { for (int l = 1; l < 64; ++l) v = fmaxf(v, scratch[w * 64 + l][q]); }
    else       { for (int l = 1; l < 64; ++l) v = fminf(v, scratch[w * 64 + l][q]); }
    bbox[w][q] = v;
  }
  __syncthreads();
  const float bx0 = bbox[wid][0], bx1 = bbox[wid][1];
  const float by0 = bbox[wid][2], by1 = bbox[wid][3];
  const float bz0 = bbox[wid][4], bz1 = bbox[wid][5];

  float cx = xs[0], cy = ys[0], cz = zs[0];
  float dmax = 1e10f;       // wave's current max min-dist (wave-uniform)
  double prev_wk = 0.0;     // valid in lane 63 whenever a skip can happen

  for (int it = 1; it < NPOINT; ++it) {
    // exact skip test: dist^2(c, bbox) >= dmax (with conservative margin)
    float ax = fmaxf(fmaxf(bx0 - cx, cx - bx1), 0.f);
    float ay = fmaxf(fmaxf(by0 - cy, cy - by1), 0.f);
    float az = fmaxf(fmaxf(bz0 - cz, cz - bz1), 0.f);
    float LB = ax * ax + ay * ay + az * az;
    int skip = (LB > dmax * 1.00002f) ? 1 : 0;
    skip = __builtin_amdgcn_readfirstlane(skip);  // wave-uniform scalar branch
    double wk;
    if (skip) {
      wk = prev_wk;  // bit-exact: min-update provably a no-op for this wave
    } else {
      double key[16];
#pragma unroll
      for (int j = 0; j < 16; ++j) {
        float dx = px[j] - cx, dy = py[j] - cy, dz = pz[j] - cz;
        float dd = dx * dx + dy * dy + dz * dz;   // same expr as rounds 1-4
        float t = fminf(dist[j], dd);
        dist[j] = t;
        key[j] = __longlong_as_double(
            (long long)(((u64)__float_as_uint(t) << 32) | klo[j]));
      }
#pragma unroll
      for (int s = 1; s < 16; s <<= 1) {
#pragma unroll
        for (int j = 0; j < 16; j += 2 * s) key[j] = MAXF64(key[j], key[j + s]);
      }
      wk = wave_max_f64(key[0]);  // lane 63 owns the true wave max
      prev_wk = wk;
    }
    if (lane == 63) kbuf[it & 1][wid] = wk;
    __syncthreads();  // the only barrier per iteration
    // all threads resolve the block winner: 4 b128 broadcasts + f64 max tree
    const double2* kb = (const double2*)&kbuf[it & 1][0];
    double2 p0 = kb[0], p1 = kb[1], p2 = kb[2], p3 = kb[3];
    double m0 = MAXF64(p0.x, p0.y), m1 = MAXF64(p1.x, p1.y);
    double m2 = MAXF64(p2.x, p2.y), m3 = MAXF64(p3.x, p3.y);
    double best = MAXF64(MAXF64(m0, m1), MAXF64(m2, m3));
    u32 widx = ~(u32)(u64)__double_as_longlong(best);  // winner point index
    if (tid == 0) cent[b * NPOINT + it] = (int)widx;
    cx = xs[widx]; cy = ys[widx]; cz = zs[widx];  // broadcast LDS reads
    // refresh wave-uniform dmax from own posted key (broadcast LDS read)
    u64 ob = (u64)__double_as_longlong(kbuf[it & 1][wid]);
    dmax = __uint_as_float((u32)(ob >> 32));
  }
}

// ---------------- Kernel 2: 16-NN per centroid + new_xyz gather ----------------
// grid NBATCH*NPOINT, block 256. 32 candidate dists per thread in registers.
// Min-extraction via inverted keys + exact u64 DPP max-reduce.
__global__ __launch_bounds__(256) void knn_kernel(const float* __restrict__ xyz,
                                                  const int* __restrict__ cent,
                                                  int* __restrict__ knn,
                                                  float* __restrict__ out_xyz) {
  const int pt = blockIdx.x;       // 0..16383
  const int b = pt >> 11;
  const int tid = threadIdx.x;
  const float* xb = xyz + (size_t)b * NPTS * 3;
  const int ci = cent[pt];
  const float mx = xb[ci * 3 + 0], my = xb[ci * 3 + 1], mz = xb[ci * 3 + 2];
  if (tid < 3) out_xyz[pt * 3 + tid] = xb[ci * 3 + tid];
  const float sm = mx * mx + my * my + mz * mz;

  float d[32];
  float lv = 3.0e38f;
  int lj = 0;
#pragma unroll
  for (int j = 0; j < 32; ++j) {
    int i = tid + 256 * j;
    float x = xb[i * 3 + 0], y = xb[i * 3 + 1], z = xb[i * 3 + 2];
    float dot = mx * x + my * y + mz * z;
    float sp = x * x + y * y + z * z;
    float dd = -2.0f * dot + sm + sp;   // same assoc as reference
    d[j] = dd;
    if (dd < lv) { lv = dd; lj = j; }
  }

  __shared__ __align__(16) u64 kbuf[2][4];
  const int lane = tid & 63;

  for (int p = 0; p < KNN_K; ++p) {
    u32 fb = __float_as_uint(lv);
    u32 mapped = (fb & 0x80000000u) ? ~fb : (fb | 0x80000000u);  // order-preserving
    u32 idx = (u32)(tid + (lj << 8));  // == point index
    // min-key (smaller d, then smaller idx) == max of inverted key
    u64 ik = ~(((u64)mapped << 32) | (u64)idx);
    u64 wk = wave_max_u64(ik);
    if (lane == 63) kbuf[p & 1][tid >> 6] = wk;
    __syncthreads();
    const ulonglong2* kb = (const ulonglong2*)&kbuf[p & 1][0];
    ulonglong2 q0 = kb[0], q1 = kb[1];
    u64 best = MAXU64(MAXU64(q0.x, q0.y), MAXU64(q1.x, q1.y));
    u32 widx = (u32)(~best);  // point index of the minimum
    if (tid == 0) knn[pt * KNN_K + p] = (int)widx;
    if (tid == (int)(widx & 255u)) {
      int j0 = (int)(widx >> 8);
      float nlv = 3.0e38f;
      int nlj = 0;
#pragma unroll
      for (int j = 0; j < 32; ++j) {
        if (j == j0) d[j] = 3.0e38f;
        if (d[j] < nlv) { nlv = d[j]; nlj = j; }
      }
      lv = nlv; lj = nlj;
    }
  }
}

// ---------------- Kernel 3: gather+GEMM + BN partials + per-(pt,o) max/min ----------------
__global__ __launch_bounds__(256) void gemm_stats_kernel(const float* __restrict__ feat,
                                                         const float* __restrict__ W,
                                                         const int* __restrict__ knn,
                                                         float* __restrict__ part,
                                                         float* __restrict__ mxbuf,
                                                         float* __restrict__ mnbuf) {
  const int tid = threadIdx.x;
  const int o0 = (tid & 63) * 2;
  const int o1 = o0 + 1;
  const int grp = tid >> 6;  // wave id, 0..3
  __shared__ __align__(16) float g[128][CIN];
  __shared__ int kidx[128];
  __shared__ float sred[4][128];

  const int rowbase = blockIdx.x * 128;
  if (tid < 128) kidx[tid] = knn[rowbase + tid];

  float4 w0v[16], w1v[16];
  {
    const float4* wv0 = (const float4*)(W + (size_t)o0 * CIN);
    const float4* wv1 = (const float4*)(W + (size_t)o1 * CIN);
#pragma unroll
    for (int q = 0; q < 16; ++q) { w0v[q] = wv0[q]; w1v[q] = wv1[q]; }
  }
  __syncthreads();
#pragma unroll
  for (int s = 0; s < 8; ++s) {
    int v = tid + 256 * s;
    int row = v >> 4, q = v & 15;
    int gr = rowbase + row;
    int bb = gr >> 15;  // 32768 rows per batch
    const float4* src = (const float4*)(feat + (size_t)(bb * NPTS + kidx[row]) * CIN);
    *((float4*)&g[row][q * 4]) = src[q];
  }
  __syncthreads();

  float s1_0 = 0.f, s2_0 = 0.f, s1_1 = 0.f, s2_1 = 0.f;
#pragma unroll
  for (int pp = 0; pp < 2; ++pp) {
    const int ptl = grp + pp * 4;  // 0..7
    float mx0 = -3.0e38f, mn0 = 3.0e38f, mx1 = -3.0e38f, mn1 = 3.0e38f;
#pragma unroll
    for (int k = 0; k < KNN_K; ++k) {
      const int row = ptl * 16 + k;
      float a0 = 0.f, a1 = 0.f;
#pragma unroll
      for (int q = 0; q < 16; ++q) {
        float4 a = *((const float4*)&g[row][q * 4]);  // broadcast within wave
        a0 += w0v[q].x * a.x + w0v[q].y * a.y + w0v[q].z * a.z + w0v[q].w * a.w;
        a1 += w1v[q].x * a.x + w1v[q].y * a.y + w1v[q].z * a.z + w1v[q].w * a.w;
      }
      s1_0 += a0; s2_0 += a0 * a0; mx0 = fmaxf(mx0, a0); mn0 = fminf(mn0, a0);
      s1_1 += a1; s2_1 += a1 * a1; mx1 = fmaxf(mx1, a1); mn1 = fminf(mn1, a1);
    }
    const size_t pt = (size_t)blockIdx.x * 8 + ptl;
    mxbuf[pt * COUT + o0] = mx0;
    mxbuf[pt * COUT + o1] = mx1;
    mnbuf[pt * COUT + o0] = mn0;
    mnbuf[pt * COUT + o1] = mn1;
  }
  sred[grp][o0] = s1_0; sred[grp][o1] = s1_1;
  __syncthreads();
  if (tid < 128) {
    float t = sred[0][tid] + sred[1][tid] + sred[2][tid] + sred[3][tid];
    part[blockIdx.x * 256 + tid] = t;
  }
  __syncthreads();
  sred[grp][o0] = s2_0; sred[grp][o1] = s2_1;
  __syncthreads();
  if (tid < 128) {
    float t = sred[0][tid] + sred[1][tid] + sred[2][tid] + sred[3][tid];
    part[blockIdx.x * 256 + 128 + tid] = t;
  }
}

// ---------------- Kernel 4: reduce partials -> scale/shift per channel ----------------
__global__ __launch_bounds__(256) void bn_reduce_kernel(const float* __restrict__ part,
                                                        const float* __restrict__ gamma,
                                                        const float* __restrict__ beta,
                                                        float* __restrict__ stats) {
  const int o = blockIdx.x;  // 128
  const int tid = threadIdx.x;
  float s1 = 0.f, s2 = 0.f;
  for (int p = tid; p < 2048; p += 256) {
    s1 += part[p * 256 + o];
    s2 += part[p * 256 + 128 + o];
  }
  __shared__ float r1[256], r2[256];
  r1[tid] = s1; r2[tid] = s2;
  __syncthreads();
  for (int s = 128; s >= 1; s >>= 1) {
    if (tid < s) { r1[tid] += r1[tid + s]; r2[tid] += r2[tid + s]; }
    __syncthreads();
  }
  if (tid == 0) {
    const float n = (float)(NBATCH * NPOINT * KNN_K);
    float mean = r1[0] / n;
    float var = r2[0] / n - mean * mean;
    float inv = rsqrtf(var + 1e-5f);
    float sc = gamma[o] * inv;
    stats[o] = sc;
    stats[128 + o] = beta[o] - mean * sc;
  }
}

// ---------------- Kernel 5: finalize out = relu(sel*sc + sh) ----------------
__global__ __launch_bounds__(256) void finalize_kernel(float* __restrict__ out_feat,
                                                       const float* __restrict__ mnbuf,
                                                       const float* __restrict__ stats) {
  const int i = blockIdx.x * 256 + threadIdx.x;  // 16384*128 total
  const int o = i & 127;
  const float sc = stats[o];
  const float sh = stats[128 + o];
  const float mx = out_feat[i];
  const float mn = mnbuf[i];
  const float sel = (sc >= 0.f) ? mx : mn;
  out_feat[i] = fmaxf(sel * sc + sh, 0.f);
}

extern "C" void kernel_launch(void* const* d_in, const int* in_sizes, int n_in,
                              void* d_out, int out_size, void* d_ws, size_t ws_size,
                              hipStream_t stream) {
  const float* xyz = (const float*)d_in[0];
  const float* feat = (const float*)d_in[1];
  const float* W = (const float*)d_in[2];
  const float* gamma = (const float*)d_in[3];
  const float* beta = (const float*)d_in[4];
  float* out = (float*)d_out;

  int* cent = (int*)d_ws;                                  // 16384 ints
  int* knn = cent + NBATCH * NPOINT;                       // 262144 ints
  float* part = (float*)(knn + NBATCH * NPOINT * KNN_K);   // 2048*256 f32
  float* stats = part + 2048 * 256;                        // 256 f32
  float* mnbuf = stats + 256;                              // 16384*128 f32

  float* out_xyz = out;                                    // [8,2048,3]
  float* out_feat = out + NBATCH * NPOINT * 3;             // [8,2048,128]

  hipLaunchKernelGGL(fps_kernel, dim3(NBATCH), dim3(512), 0, stream, xyz, cent);
  hipLaunchKernelGGL(knn_kernel, dim3(NBATCH * NPOINT), dim3(256), 0, stream,
                     xyz, cent, knn, out_xyz);
  hipLaunchKernelGGL(gemm_stats_kernel, dim3(2048), dim3(256), 0, stream,
                     feat, W, knn, part, out_feat, mnbuf);
  hipLaunchKernelGGL(bn_reduce_kernel, dim3(128), dim3(256), 0, stream,
                     part, gamma, beta, stats);
  hipLaunchKernelGGL(finalize_kernel, dim3(8192), dim3(256), 0, stream,
                     out_feat, mnbuf, stats);
}